// Round 6
// baseline (506.755 us; speedup 1.0000x reference)
//
#include <hip/hip_runtime.h>
#include <hip/hip_bf16.h>
#include <stdint.h>
#include <stddef.h>

// Problem constants (from reference setup_inputs)
#define N_NODES 8192
#define DIM     256
#define BATCH   4096
#define CLASSES 1000
#define ALPHA_C 1.0f
#define BETA_C  0.01f
#define GAMMA_C 0.1f

// GEMM decomposition: mean(adj*(1-sim)) = (Sum[a] - <A*U, U>)/N^2 with U the
// row-normalized embeddings (sim = U U^T). W = A*U streams adj through MFMA
// exactly once (268 MB -> ~43 us HBM floor).
//
// KEY CHANGE (R6): adj is read in 1 KB-contiguous per-wave-instruction runs
// (64 lanes x float4 on ONE row) instead of 256 B-per-row scatter at 32 KB
// stride (power-of-2 stride = HBM channel aliasing -> ~1.8 TB/s in R1-R5).
#define KSPLIT  16
#define KRANGE  (N_NODES / KSPLIT)   // 512
#define SUPER   256                  // A staged per super-chunk of 256 k
#define NSUPER  (KRANGE / SUPER)     // 2
#define BK      64                   // MFMA K-chunk within a super
#define NBK     (SUPER / BK)         // 4
#define BM      64

typedef __bf16 bf16_t;
typedef __bf16 bf16x4 __attribute__((ext_vector_type(4)));
typedef __bf16 bf16x8 __attribute__((ext_vector_type(8)));
typedef float  f32x4  __attribute__((ext_vector_type(4)));
typedef float  f32x16 __attribute__((ext_vector_type(16)));

// Async global->LDS DMA, 16 B/lane, dest = wave-uniform base + lane*16.
__device__ __forceinline__ void async16(const void* g, void* l) {
  __builtin_amdgcn_global_load_lds(
      (const __attribute__((address_space(1))) uint32_t*)g,
      (__attribute__((address_space(3))) uint32_t*)l, 16, 0, 0);
}

// ---------------------------------------------------------------------------
// prep_norm: L2-normalize each embedding row (fp32 math), store U bf16.
// ---------------------------------------------------------------------------
__global__ __launch_bounds__(256) void prep_norm(
    const float* __restrict__ emb, bf16_t* __restrict__ U) {
  const int row = blockIdx.x;
  const int t = threadIdx.x;
  const float v = emb[(size_t)row * DIM + t];
  float sq = v * v;
  for (int off = 32; off; off >>= 1) sq += __shfl_down(sq, off);
  __shared__ float red[4];
  if ((t & 63) == 0) red[t >> 6] = sq;
  __syncthreads();
  const float total = red[0] + red[1] + red[2] + red[3];
  U[(size_t)row * DIM + t] = (bf16_t)(v * rsqrtf(total));
}

// ---------------------------------------------------------------------------
// prep_transpose: V = U^T via 64x64 LDS tiles, 16 B coalesced both sides.
// ---------------------------------------------------------------------------
#define TP 68  // padded LDS row stride (bf16 elems)

__global__ __launch_bounds__(256) void prep_transpose(
    const bf16_t* __restrict__ U, bf16_t* __restrict__ V) {
  __shared__ bf16_t tile[64 * TP];
  const int k0 = blockIdx.x * 64;  // node block
  const int d0 = blockIdx.y * 64;  // dim block
  const int t = threadIdx.x;
  const int r = t >> 3;            // 0..31
  const int c8 = t & 7;            // 16B chunk

  *(bf16x8*)&tile[r * TP + c8 * 8] =
      *(const bf16x8*)&U[(size_t)(k0 + r) * DIM + d0 + c8 * 8];
  *(bf16x8*)&tile[(r + 32) * TP + c8 * 8] =
      *(const bf16x8*)&U[(size_t)(k0 + r + 32) * DIM + d0 + c8 * 8];
  __syncthreads();

  bf16x8 o0, o1;
#pragma unroll
  for (int j = 0; j < 8; ++j) {
    o0[j] = tile[(c8 * 8 + j) * TP + r];
    o1[j] = tile[(c8 * 8 + j) * TP + r + 32];
  }
  *(bf16x8*)&V[(size_t)(d0 + r) * N_NODES + k0 + c8 * 8] = o0;
  *(bf16x8*)&V[(size_t)(d0 + r + 32) * N_NODES + k0 + c8 * 8] = o1;
}

// ---------------------------------------------------------------------------
// Cross-entropy: one block per batch row; single global pass, logits in regs.
// ---------------------------------------------------------------------------
__global__ __launch_bounds__(256) void ce_kernel(
    const float* __restrict__ pred, const int* __restrict__ target,
    float* __restrict__ out) {
  const int row = blockIdx.x;
  const int t = threadIdx.x;
  const float* p = pred + (size_t)row * CLASSES;

  float v[4];
  for (int k = 0; k < 4; ++k) {
    const int c = t + k * 256;
    v[k] = (c < CLASSES) ? p[c] : -INFINITY;
  }

  float m = fmaxf(fmaxf(v[0], v[1]), fmaxf(v[2], v[3]));
  for (int off = 32; off; off >>= 1) m = fmaxf(m, __shfl_down(m, off));

  __shared__ float red[8];
  const int wave = t >> 6, lane = t & 63;
  if (lane == 0) red[wave] = m;
  __syncthreads();
  if (t == 0) red[4] = fmaxf(fmaxf(red[0], red[1]), fmaxf(red[2], red[3]));
  __syncthreads();
  const float mx = red[4];

  float s = 0.f;
  for (int k = 0; k < 4; ++k) s += __expf(v[k] - mx);
  for (int off = 32; off; off >>= 1) s += __shfl_down(s, off);
  if (lane == 0) red[wave] = s;
  __syncthreads();
  if (t == 0) {
    float ssum = red[0] + red[1] + red[2] + red[3];
    float lse = mx + __logf(ssum);
    float loss = lse - p[target[row]];
    atomicAdd(out, loss * (ALPHA_C / (float)BATCH));
  }
}

// ---------------------------------------------------------------------------
// Fused W = A*U tile + Sum[a], Sum[|a|] + epilogue <W,U> dot.
//
// A: both 256-k super-chunks prefetched up front as ROW-LINEAR loads:
//    wave w, instr j -> 1 KB contiguous of adj row (i0 + w*16 + j).
//    cvt to bf16 into As[64][256] (32 KB) with 32-chunk XOR swizzle
//    (16B chunk c of row r stored at position c ^ (r & 31)).
// B: per-BK cooperative DMA into Bs[256 d][64 k] (32 KB, R5 swizzle);
//    wave w stages and reads only its own d-slice (no cross-wave hazard).
// Compute: wave w owns d-cols [w*64, w*64+64) x 64 rows = 2x2 of
//    v_mfma_f32_32x32x16_bf16.
// LDS 65 KB -> 2 blocks/CU; VGPR budget 256 (launch_bounds(256,2)):
//    pf 128 + acc 64 + frags fits without spill.
// ---------------------------------------------------------------------------
__global__ __launch_bounds__(256, 2) void gemm_kernel(
    const float* __restrict__ adj, const bf16_t* __restrict__ U,
    const bf16_t* __restrict__ V, float* __restrict__ out) {
  __shared__ __align__(16) bf16_t As[BM * SUPER];   // 32 KB
  __shared__ __align__(16) bf16_t Bs[DIM * BK];     // 32 KB
  __shared__ float red[4];

  const int i0 = blockIdx.x * BM;
  const int kbase = blockIdx.y * KRANGE;
  const int t = threadIdx.x;
  const int w = t >> 6, lane = t & 63;
  const int m = lane & 31, h = lane >> 5;
  // B staging lane mapping (as R5).
  const int srow = lane >> 3;
  const int sch = (lane & 7) ^ srow;

  // ---- A prefetch: both supers, row-linear (1 KB per wave-instr) ----
  const float* arow =
      adj + (size_t)(i0 + w * 16) * N_NODES + kbase + lane * 4;
  float4 pf0[16], pf1[16];
#pragma unroll
  for (int j = 0; j < 16; ++j)
    pf0[j] = *(const float4*)(arow + (size_t)j * N_NODES);
#pragma unroll
  for (int j = 0; j < 16; ++j)
    pf1[j] = *(const float4*)(arow + (size_t)j * N_NODES + SUPER);

  f32x16 acc[2][2] = {};
  float sa = 0.f, sabs = 0.f;

#pragma unroll
  for (int s = 0; s < NSUPER; ++s) {
    // super0: drains the A prefetches; super1: all waves done reading As.
    __syncthreads();

    // ---- cvt + sums + swizzled As write (this super's 16 rows/wave) ----
#pragma unroll
    for (int j = 0; j < 16; ++j) {
      const float4 v = s ? pf1[j] : pf0[j];
      sa += v.x + v.y + v.z + v.w;
      sabs += fabsf(v.x) + fabsf(v.y) + fabsf(v.z) + fabsf(v.w);
      const int r = w * 16 + j;
      bf16x4 c;
      c[0] = (bf16_t)v.x; c[1] = (bf16_t)v.y;
      c[2] = (bf16_t)v.z; c[3] = (bf16_t)v.w;
      const int pos = (((lane >> 1) ^ (r & 31)) & 31) * 8 + (lane & 1) * 4;
      *(bf16x4*)&As[r * SUPER + pos] = c;
    }

#pragma unroll
    for (int bk = 0; bk < NBK; ++bk) {
      const int k0 = kbase + s * SUPER + bk * BK;
      // B DMA: wave w stages its own d-slice (8 async16).
#pragma unroll
      for (int q = 0; q < 8; ++q) {
        const int dbase = w * 64 + q * 8;  // wave-uniform
        async16(V + (size_t)(dbase + srow) * N_NODES + k0 + sch * 8,
                &Bs[dbase * 64]);
      }
      // Barrier: publishes As (bk==0) and drains the B DMA (vmcnt0).
      __syncthreads();

#pragma unroll
      for (int kk = 0; kk < 4; ++kk) {
        const int qa = bk * 8 + kk * 2 + h;  // As 16B-chunk index 0..31
        const int pa = ((qa ^ m) & 31) * 8;
        bf16x8 a0 = *(const bf16x8*)&As[m * SUPER + pa];
        bf16x8 a1 = *(const bf16x8*)&As[(m + 32) * SUPER + pa];
        const int pb = ((kk * 2 + h) ^ (m & 7)) * 8;
        bf16x8 b0 = *(const bf16x8*)&Bs[(w * 64 + m) * 64 + pb];
        bf16x8 b1 = *(const bf16x8*)&Bs[(w * 64 + 32 + m) * 64 + pb];
        acc[0][0] = __builtin_amdgcn_mfma_f32_32x32x16_bf16(a0, b0, acc[0][0],
                                                            0, 0, 0);
        acc[0][1] = __builtin_amdgcn_mfma_f32_32x32x16_bf16(a0, b1, acc[0][1],
                                                            0, 0, 0);
        acc[1][0] = __builtin_amdgcn_mfma_f32_32x32x16_bf16(a1, b0, acc[1][0],
                                                            0, 0, 0);
        acc[1][1] = __builtin_amdgcn_mfma_f32_32x32x16_bf16(a1, b1, acc[1][1],
                                                            0, 0, 0);
      }
    }
  }

  // Epilogue: simdot = <acc, U-tile>. C/D layout (32x32):
  // col = lane&31 (d), row = (reg&3) + 8*(reg>>2) + 4*(lane>>5) (i).
  float simdot = 0.f;
#pragma unroll
  for (int mi = 0; mi < 2; ++mi) {
#pragma unroll
    for (int nd = 0; nd < 2; ++nd) {
      const int ib = i0 + mi * 32 + 4 * h;
      const int d = w * 64 + nd * 32 + m;
      const bf16_t* up = U + (size_t)ib * DIM + d;
#pragma unroll
      for (int rg = 0; rg < 16; ++rg) {
        const int row = (rg & 3) + 8 * (rg >> 2);
        simdot += (float)up[(size_t)row * DIM] * acc[mi][nd][rg];
      }
    }
  }

  float local = BETA_C * sabs + GAMMA_C * (sa - simdot);
  for (int off = 32; off; off >>= 1) local += __shfl_down(local, off);
  if (lane == 0) red[w] = local;
  __syncthreads();
  if (t == 0) {
    const float inv = 1.f / ((float)N_NODES * (float)N_NODES);
    atomicAdd(out, (red[0] + red[1] + red[2] + red[3]) * inv);
  }
}

// ---------------------------------------------------------------------------
extern "C" void kernel_launch(void* const* d_in, const int* in_sizes, int n_in,
                              void* d_out, int out_size, void* d_ws,
                              size_t ws_size, hipStream_t stream) {
  const float* pred   = (const float*)d_in[0];
  const int*   target = (const int*)d_in[1];
  const float* adj    = (const float*)d_in[2];
  const float* emb    = (const float*)d_in[3];
  float* out = (float*)d_out;

  bf16_t* U = (bf16_t*)d_ws;                                       // 4 MB
  bf16_t* V = (bf16_t*)((char*)d_ws + (size_t)N_NODES * DIM * 2);  // 4 MB

  hipMemsetAsync(d_out, 0, sizeof(float), stream);
  ce_kernel<<<BATCH, 256, 0, stream>>>(pred, target, out);
  prep_norm<<<N_NODES, 256, 0, stream>>>(emb, U);
  prep_transpose<<<dim3(N_NODES / 64, DIM / 64), 256, 0, stream>>>(U, V);
  gemm_kernel<<<dim3(N_NODES / BM, KSPLIT), 256, 0, stream>>>(adj, U, V, out);
}

// Round 7
// 504.762 us; speedup vs baseline: 1.0039x; 1.0039x over previous
//
#include <hip/hip_runtime.h>
#include <hip/hip_bf16.h>
#include <stdint.h>
#include <stddef.h>

// Problem constants (from reference setup_inputs)
#define N_NODES 8192
#define DIM     256
#define BATCH   4096
#define CLASSES 1000
#define ALPHA_C 1.0f
#define BETA_C  0.01f
#define GAMMA_C 0.1f

// mean(adj*(1-sim)) = (Sum[a] - <A*U, U>)/N^2, U = row-normalized embeddings.
// W = A*U streams adj through MFMA exactly once (268 MB ~ 43 us HBM floor).
//
// R7 KEY CHANGE: per-block k-phase ROTATION. All previous rounds read adj at
// k-offsets quantized to 2 KB within 32 KB-strided rows -> every resident
// block hits the same channel-interleave phases simultaneously (~1.2-1.8
// TB/s in R1-R6 vs 6.7 TB/s for linear fills). Blocks now start their
// super-chunk walk at phase (bx*5+by*7) mod 16, so concurrent blocks cover
// all 32 1KB-phases of the 32 KB row period.
#define BM      32
#define KSPLIT  2
#define KRANGE  (N_NODES / KSPLIT)   // 4096
#define SUPER   256                  // k elems per A-staging super-chunk (1 KB/row)
#define NSUP    (KRANGE / SUPER)     // 16

typedef __bf16 bf16_t;
typedef __bf16 bf16x4 __attribute__((ext_vector_type(4)));
typedef __bf16 bf16x8 __attribute__((ext_vector_type(8)));
typedef float  f32x16 __attribute__((ext_vector_type(16)));

// Async global->LDS DMA, 16 B/lane, dest = wave-uniform base + lane*16.
__device__ __forceinline__ void async16(const void* g, void* l) {
  __builtin_amdgcn_global_load_lds(
      (const __attribute__((address_space(1))) uint32_t*)g,
      (__attribute__((address_space(3))) uint32_t*)l, 16, 0, 0);
}

// ---------------------------------------------------------------------------
// prep_norm: L2-normalize each embedding row (fp32 math), store U bf16.
// ---------------------------------------------------------------------------
__global__ __launch_bounds__(256) void prep_norm(
    const float* __restrict__ emb, bf16_t* __restrict__ U) {
  const int row = blockIdx.x;
  const int t = threadIdx.x;
  const float v = emb[(size_t)row * DIM + t];
  float sq = v * v;
  for (int off = 32; off; off >>= 1) sq += __shfl_down(sq, off);
  __shared__ float red[4];
  if ((t & 63) == 0) red[t >> 6] = sq;
  __syncthreads();
  const float total = red[0] + red[1] + red[2] + red[3];
  U[(size_t)row * DIM + t] = (bf16_t)(v * rsqrtf(total));
}

// ---------------------------------------------------------------------------
// prep_transpose: V = U^T via 64x64 LDS tiles, 16 B coalesced both sides.
// ---------------------------------------------------------------------------
#define TP 68  // padded LDS row stride (bf16 elems)

__global__ __launch_bounds__(256) void prep_transpose(
    const bf16_t* __restrict__ U, bf16_t* __restrict__ V) {
  __shared__ bf16_t tile[64 * TP];
  const int k0 = blockIdx.x * 64;  // node block
  const int d0 = blockIdx.y * 64;  // dim block
  const int t = threadIdx.x;
  const int r = t >> 3;            // 0..31
  const int c8 = t & 7;            // 16B chunk

  *(bf16x8*)&tile[r * TP + c8 * 8] =
      *(const bf16x8*)&U[(size_t)(k0 + r) * DIM + d0 + c8 * 8];
  *(bf16x8*)&tile[(r + 32) * TP + c8 * 8] =
      *(const bf16x8*)&U[(size_t)(k0 + r + 32) * DIM + d0 + c8 * 8];
  __syncthreads();

  bf16x8 o0, o1;
#pragma unroll
  for (int j = 0; j < 8; ++j) {
    o0[j] = tile[(c8 * 8 + j) * TP + r];
    o1[j] = tile[(c8 * 8 + j) * TP + r + 32];
  }
  *(bf16x8*)&V[(size_t)(d0 + r) * N_NODES + k0 + c8 * 8] = o0;
  *(bf16x8*)&V[(size_t)(d0 + r + 32) * N_NODES + k0 + c8 * 8] = o1;
}

// ---------------------------------------------------------------------------
// Cross-entropy: one block per batch row; single global pass, logits in regs.
// ---------------------------------------------------------------------------
__global__ __launch_bounds__(256) void ce_kernel(
    const float* __restrict__ pred, const int* __restrict__ target,
    float* __restrict__ out) {
  const int row = blockIdx.x;
  const int t = threadIdx.x;
  const float* p = pred + (size_t)row * CLASSES;

  float v[4];
  for (int k = 0; k < 4; ++k) {
    const int c = t + k * 256;
    v[k] = (c < CLASSES) ? p[c] : -INFINITY;
  }

  float m = fmaxf(fmaxf(v[0], v[1]), fmaxf(v[2], v[3]));
  for (int off = 32; off; off >>= 1) m = fmaxf(m, __shfl_down(m, off));

  __shared__ float red[8];
  const int wave = t >> 6, lane = t & 63;
  if (lane == 0) red[wave] = m;
  __syncthreads();
  if (t == 0) red[4] = fmaxf(fmaxf(red[0], red[1]), fmaxf(red[2], red[3]));
  __syncthreads();
  const float mx = red[4];

  float s = 0.f;
  for (int k = 0; k < 4; ++k) s += __expf(v[k] - mx);
  for (int off = 32; off; off >>= 1) s += __shfl_down(s, off);
  if (lane == 0) red[wave] = s;
  __syncthreads();
  if (t == 0) {
    float ssum = red[0] + red[1] + red[2] + red[3];
    float lse = mx + __logf(ssum);
    float loss = lse - p[target[row]];
    atomicAdd(out, loss * (ALPHA_C / (float)BATCH));
  }
}

// ---------------------------------------------------------------------------
// Fused W = A*U (BM=32 rows x D=256) + Sum[a], Sum[|a|] + <W,U> epilogue.
//
// Per super (256 k): A staged as 1 KB-per-row linear reads (wave w rows
// w*8..w*8+7, one float4/lane), cvt->bf16 into XOR-swizzled As[32][256]
// (16 KB). B: per-wave-PRIVATE d-slice DMA into double-buffered
// Bs[2][256][64] (64 KB total) -> inner bk loop needs NO barrier, only
// s_waitcnt vmcnt(0) (waits own B DMA; A prefetch is issued later at bk3 so
// it is never force-drained mid-super). 2 barriers per super (As hazard).
// Wave w: d-cols [w*64,w*64+64) x 32 rows = 2 x v_mfma_f32_32x32x16_bf16
// per k-step. LDS 80 KB -> 2 blocks/CU. VGPRs ~90 -> no spill.
// ---------------------------------------------------------------------------
__global__ __launch_bounds__(256) void gemm_kernel(
    const float* __restrict__ adj, const bf16_t* __restrict__ U,
    const bf16_t* __restrict__ V, float* __restrict__ out) {
  __shared__ __align__(16) bf16_t As[BM * SUPER];    // 16 KB
  __shared__ __align__(16) bf16_t Bs[2][DIM * 64];   // 64 KB
  __shared__ float red[4];

  const int bx = blockIdx.x, by = blockIdx.y;
  const int i0 = bx * BM;
  const int kbase = by * KRANGE;
  const int t = threadIdx.x;
  const int w = t >> 6, lane = t & 63;
  const int m = lane & 31, h = lane >> 5;
  const int srow = lane >> 3;
  const int sch = (lane & 7) ^ (srow & 7);
  const int sstart = (bx * 5 + by * 7) & (NSUP - 1);  // k-phase rotation

  const float* arow = adj + (size_t)(i0 + w * 8) * N_NODES + lane * 4;

  auto issueB = [&](int buf, int k0) {
#pragma unroll
    for (int q = 0; q < 8; ++q) {
      const int dbase = w * 64 + q * 8;  // wave-uniform
      async16(V + (size_t)(dbase + srow) * N_NODES + k0 + sch * 8,
              &Bs[buf][dbase * 64]);
    }
  };

  f32x16 acc[2] = {};

  auto compute = [&](int buf, int bk) {
#pragma unroll
    for (int kk = 0; kk < 4; ++kk) {
      const int qa = bk * 8 + kk * 2 + h;            // As 16B-chunk 0..31
      const int pa = ((qa ^ m) & 31) * 8;
      bf16x8 a0 = *(const bf16x8*)&As[m * SUPER + pa];
      const int pb = ((kk * 2 + h) ^ (m & 7)) * 8;
      bf16x8 b0 = *(const bf16x8*)&Bs[buf][(w * 64 + m) * 64 + pb];
      bf16x8 b1 = *(const bf16x8*)&Bs[buf][(w * 64 + 32 + m) * 64 + pb];
      acc[0] = __builtin_amdgcn_mfma_f32_32x32x16_bf16(a0, b0, acc[0], 0, 0, 0);
      acc[1] = __builtin_amdgcn_mfma_f32_32x32x16_bf16(a0, b1, acc[1], 0, 0, 0);
    }
  };

  float sa = 0.f, sabs = 0.f;

  // Prefetch first super's A (8 x 1 KB linear runs per wave).
  float4 pf[8];
  {
    const int ks = kbase + sstart * SUPER;
#pragma unroll
    for (int j = 0; j < 8; ++j)
      pf[j] = *(const float4*)(arow + (size_t)j * N_NODES + ks);
  }

  for (int si = 0; si < NSUP; ++si) {
    const int s = (sstart + si) & (NSUP - 1);
    const int ks = kbase + s * SUPER;

    __syncthreads();  // all waves done reading As of previous super

    issueB(0, ks);    // B for bk0 (drained by barrier below)

    // cvt + sums + swizzled As write (16B chunk c of row r at c^(r&31))
#pragma unroll
    for (int j = 0; j < 8; ++j) {
      const float4 v = pf[j];
      sa += v.x + v.y + v.z + v.w;
      sabs += fabsf(v.x) + fabsf(v.y) + fabsf(v.z) + fabsf(v.w);
      const int r = w * 8 + j;
      bf16x4 c;
      c[0] = (bf16_t)v.x; c[1] = (bf16_t)v.y;
      c[2] = (bf16_t)v.z; c[3] = (bf16_t)v.w;
      const int pos = (((lane >> 1) ^ (r & 31)) & 31) * 8 + (lane & 1) * 4;
      *(bf16x4*)&As[r * SUPER + pos] = c;
    }
    __syncthreads();  // publish As; drains B0 (own slice)

    // bk0: prefetch B1, compute from Bs[0]
    issueB(1, ks + 64);
    compute(0, 0);
    // bk1: wait own B1 (nothing older in flight), prefetch B2, compute Bs[1]
    __builtin_amdgcn_s_waitcnt(0x0f70);  // vmcnt(0)
    issueB(0, ks + 128);
    compute(1, 1);
    // bk2
    __builtin_amdgcn_s_waitcnt(0x0f70);
    issueB(1, ks + 192);
    compute(0, 2);
    // bk3: wait B3, then issue next super's A prefetch (drained at barrier 1)
    __builtin_amdgcn_s_waitcnt(0x0f70);
    if (si + 1 < NSUP) {
      const int kn = kbase + ((sstart + si + 1) & (NSUP - 1)) * SUPER;
#pragma unroll
      for (int j = 0; j < 8; ++j)
        pf[j] = *(const float4*)(arow + (size_t)j * N_NODES + kn);
    }
    compute(1, 3);
  }

  // Epilogue: simdot = <acc, U-tile>. C/D (32x32): col = lane&31 (d),
  // row = (reg&3) + 8*(reg>>2) + 4*(lane>>5) (i, 0..31).
  float simdot = 0.f;
#pragma unroll
  for (int nd = 0; nd < 2; ++nd) {
    const int d = w * 64 + nd * 32 + m;
    const bf16_t* up = U + (size_t)(i0 + 4 * h) * DIM + d;
#pragma unroll
    for (int rg = 0; rg < 16; ++rg) {
      const int row = (rg & 3) + 8 * (rg >> 2);
      simdot += (float)up[(size_t)row * DIM] * acc[nd][rg];
    }
  }

  float local = BETA_C * sabs + GAMMA_C * (sa - simdot);
  for (int off = 32; off; off >>= 1) local += __shfl_down(local, off);
  if (lane == 0) red[w] = local;
  __syncthreads();
  if (t == 0) {
    const float inv = 1.f / ((float)N_NODES * (float)N_NODES);
    atomicAdd(out, (red[0] + red[1] + red[2] + red[3]) * inv);
  }
}

// ---------------------------------------------------------------------------
extern "C" void kernel_launch(void* const* d_in, const int* in_sizes, int n_in,
                              void* d_out, int out_size, void* d_ws,
                              size_t ws_size, hipStream_t stream) {
  const float* pred   = (const float*)d_in[0];
  const int*   target = (const int*)d_in[1];
  const float* adj    = (const float*)d_in[2];
  const float* emb    = (const float*)d_in[3];
  float* out = (float*)d_out;

  bf16_t* U = (bf16_t*)d_ws;                                       // 4 MB
  bf16_t* V = (bf16_t*)((char*)d_ws + (size_t)N_NODES * DIM * 2);  // 4 MB

  hipMemsetAsync(d_out, 0, sizeof(float), stream);
  ce_kernel<<<BATCH, 256, 0, stream>>>(pred, target, out);
  prep_norm<<<N_NODES, 256, 0, stream>>>(emb, U);
  prep_transpose<<<dim3(N_NODES / 64, DIM / 64), 256, 0, stream>>>(U, V);
  gemm_kernel<<<dim3(N_NODES / BM, KSPLIT), 256, 0, stream>>>(adj, U, V, out);
}